// Round 3
// baseline (1760.484 us; speedup 1.0000x reference)
//
#include <hip/hip_runtime.h>

#define TSTEPS 128
#define NIN 24
#define HD 128
#define BT 16
#define NTILE 128            // 2048 / BT batch tiles
#define NTH 512

// LDS geometry (units: _Float16 elements)
#define RS    136            // h-panel row stride (16B-aligned rows, 2-way bank alias only)
#define SLOT  (BT*RS)        // 2176
#define RINGN 9              // producer: 9-slot h0 ring (8 dumped + 1 current)
// consumer overlay of the same dynamic LDS:
#define HBC_OFF 0            // [2 bufs][4 steps][SLOT] = 8*SLOT
#define B2C_OFF (8*SLOT)     // [2][SLOT] h2 double buffer
// dynamic LDS request: > 80 KiB forces exactly 1 block/CU (2 blocks would need
// >160 KiB) -> 256 blocks land on 256 CUs, halving the per-SIMD trans floor.
#define DYN_LDS 86016        // 84 KiB

// workspace layout: [flags: NTILE u32, padded to 4 KB][h1 stream: NTILE][T][BT][HD] f16
#define WS_FLAGS_PAD 4096
#define WS_TILE ((size_t)TSTEPS * BT * HD)
#define WS_NEED (WS_FLAGS_PAD + (size_t)NTILE * WS_TILE * 2)

typedef _Float16 half8  __attribute__((ext_vector_type(8)));
typedef _Float16 half4v __attribute__((ext_vector_type(4)));
typedef float    floatx4 __attribute__((ext_vector_type(4)));

__device__ __forceinline__ float sigf(float x) {
    return __builtin_amdgcn_rcpf(1.0f + __expf(-x));
}
__device__ __forceinline__ float tanh_f(float x) {
    return 1.0f - 2.0f * __builtin_amdgcn_rcpf(1.0f + __expf(2.0f * x));
}

__device__ __forceinline__ half8 ldw8(const float* p) {
    const float4* q = (const float4*)p;
    float4 a = q[0], b = q[1];
    half8 r;
    r[0] = (_Float16)a.x; r[1] = (_Float16)a.y; r[2] = (_Float16)a.z; r[3] = (_Float16)a.w;
    r[4] = (_Float16)b.x; r[5] = (_Float16)b.y; r[6] = (_Float16)b.z; r[7] = (_Float16)b.w;
    return r;
}

// =====================================================================
// Pipelined kernel: even blocks = layer-0 producer, odd blocks = layer-1
// consumer for the same batch tile. 84 KiB LDS/block -> exactly 1
// block/CU -> all 256 blocks co-resident (no deadlock) and each CU runs
// only ONE role's trans/MFMA load.
// Cross-block data path: non-temporal stores/loads (bypass per-XCD L2,
// meet at the die-level Infinity Cache) + all-thread __threadfence()
// around the flag handshake (every wave flushes/invalidates its own
// path — tid0-only fencing proved leaky under workspace re-poisoning).
// =====================================================================
__global__ __launch_bounds__(NTH, 2)
void lstm2_pipe(const float* __restrict__ x,
                const float* __restrict__ Wih0, const float* __restrict__ Whh0,
                const float* __restrict__ bih0, const float* __restrict__ bhh0,
                const float* __restrict__ Wih1, const float* __restrict__ Whh1,
                const float* __restrict__ bih1, const float* __restrict__ bhh1,
                const float* __restrict__ Wfc,  const float* __restrict__ bfc,
                float* __restrict__ out,
                _Float16* __restrict__ h1s, unsigned int* __restrict__ flags)
{
    extern __shared__ __align__(16) _Float16 SM[];

    const int tid  = threadIdx.x;
    const int blk  = blockIdx.x;
    const int tile = blk >> 1;
    const int wv   = tid >> 6;
    const int ln   = tid & 63;
    const int qd   = ln >> 4;
    const int nn   = ln & 15;
    const int b0   = tile * BT;
    const int jc   = wv * 16 + nn;
    const size_t wsbase = (size_t)tile * WS_TILE;   // f16 units into h1s

    const half8 z8 = {0, 0, 0, 0, 0, 0, 0, 0};

    if (!(blk & 1)) {
        // ================= PRODUCER: layer 0 =================
        for (int i = tid * 8; i < RINGN * SLOT; i += NTH * 8) *(half8*)&SM[i] = z8;

        float bias0[4];
        half8 wih0[4];
        half8 whh0[4][4];
#pragma unroll
        for (int tI = 0; tI < 4; ++tI) {
            int g = tI * HD + wv * 16 + nn;
            bias0[tI] = bih0[g] + bhh0[g];
            wih0[tI] = (qd < 3) ? ldw8(Wih0 + g * NIN + qd * 8) : z8;
#pragma unroll
            for (int kk = 0; kk < 4; ++kk)
                whh0[tI][kk] = ldw8(Whh0 + g * HD + kk * 32 + qd * 8);
        }

        const float* xrow = x + (size_t)(b0 + nn) * (TSTEPS * NIN) + (qd < 3 ? qd * 8 : 16);
        float4 pf0 = *(const float4*)(xrow);
        float4 pf1 = *(const float4*)(xrow + 4);

        float cs0[4] = {0.f, 0.f, 0.f, 0.f};

        __syncthreads();

        // ---- iter 0 (h0[-1]=0: only x MFMA) ----
        {
            half8 ax;
            ax[0] = (_Float16)pf0.x; ax[1] = (_Float16)pf0.y; ax[2] = (_Float16)pf0.z; ax[3] = (_Float16)pf0.w;
            ax[4] = (_Float16)pf1.x; ax[5] = (_Float16)pf1.y; ax[6] = (_Float16)pf1.z; ax[7] = (_Float16)pf1.w;
            pf0 = *(const float4*)(xrow + NIN);
            pf1 = *(const float4*)(xrow + NIN + 4);

            floatx4 acc[4];
#pragma unroll
            for (int tI = 0; tI < 4; ++tI) {
                floatx4 a = {bias0[tI], bias0[tI], bias0[tI], bias0[tI]};
                acc[tI] = __builtin_amdgcn_mfma_f32_16x16x32_f16(ax, wih0[tI], a, 0, 0, 0);
            }
#pragma unroll
            for (int r = 0; r < 4; ++r) {
                float iv = sigf(acc[0][r]);
                float gv = tanh_f(acc[2][r]);
                float ov = sigf(acc[3][r]);
                float cn = iv * gv;
                cs0[r] = cn;
                SM[(qd * 4 + r) * RS + jc] = (_Float16)(ov * tanh_f(cn));   // slot 0
            }
        }

#pragma unroll 1
        for (int t = 1; t < TSTEPS; ++t) {
            __syncthreads();   // ring slot t-1 visible

            if ((t & 7) == 0) {
                // dump chunk (t/8 - 1): times t-8..t-1; slots disjoint from slot t%9
                const int c = (t >> 3) - 1;
#pragma unroll
                for (int k = 0; k < 4; ++k) {
                    int e  = tid + k * NTH;        // 0..2047 b128-units
                    int ti = e >> 8;
                    int r  = e & 255;
                    int b  = r >> 4;
                    int c8 = (r & 15) * 8;
                    int tau = c * 8 + ti;
                    half8 v = *(const half8*)&SM[(tau % 9) * SLOT + b * RS + c8];
                    __builtin_nontemporal_store(v,
                        (half8*)(h1s + wsbase + ((size_t)tau * BT + b) * HD + c8));
                }
                __threadfence();   // every wave: drain + flush its own stores
                __syncthreads();
                if (tid == 0)
                    __hip_atomic_store(&flags[tile], (unsigned)(t >> 3),
                                       __ATOMIC_RELEASE, __HIP_MEMORY_SCOPE_AGENT);
            }

            half8 ax;
            ax[0] = (_Float16)pf0.x; ax[1] = (_Float16)pf0.y; ax[2] = (_Float16)pf0.z; ax[3] = (_Float16)pf0.w;
            ax[4] = (_Float16)pf1.x; ax[5] = (_Float16)pf1.y; ax[6] = (_Float16)pf1.z; ax[7] = (_Float16)pf1.w;
            {
                const int tn = (t < TSTEPS - 1) ? t + 1 : TSTEPS - 1;
                pf0 = *(const float4*)(xrow + tn * NIN);
                pf1 = *(const float4*)(xrow + tn * NIN + 4);
            }

            const int sprev = (t + 8) % 9;
            half8 ah[4];
#pragma unroll
            for (int kk = 0; kk < 4; ++kk)
                ah[kk] = *(const half8*)&SM[sprev * SLOT + nn * RS + kk * 32 + qd * 8];

            floatx4 acc[4];
#pragma unroll
            for (int tI = 0; tI < 4; ++tI) {
                floatx4 a = {bias0[tI], bias0[tI], bias0[tI], bias0[tI]};
                a = __builtin_amdgcn_mfma_f32_16x16x32_f16(ax, wih0[tI], a, 0, 0, 0);
#pragma unroll
                for (int kk = 0; kk < 4; ++kk)
                    a = __builtin_amdgcn_mfma_f32_16x16x32_f16(ah[kk], whh0[tI][kk], a, 0, 0, 0);
                acc[tI] = a;
            }

            const int scur = t % 9;
#pragma unroll
            for (int r = 0; r < 4; ++r) {
                float iv = sigf(acc[0][r]);
                float fv = sigf(acc[1][r]);
                float gv = tanh_f(acc[2][r]);
                float ov = sigf(acc[3][r]);
                float cn = fv * cs0[r] + iv * gv;
                cs0[r] = cn;
                SM[scur * SLOT + (qd * 4 + r) * RS + jc] = (_Float16)(ov * tanh_f(cn));
            }
        }

        __syncthreads();
        // final dump: chunk 15 (times 120..127)
        {
            const int c = 15;
#pragma unroll
            for (int k = 0; k < 4; ++k) {
                int e  = tid + k * NTH;
                int ti = e >> 8;
                int r  = e & 255;
                int b  = r >> 4;
                int c8 = (r & 15) * 8;
                int tau = c * 8 + ti;
                half8 v = *(const half8*)&SM[(tau % 9) * SLOT + b * RS + c8];
                __builtin_nontemporal_store(v,
                    (half8*)(h1s + wsbase + ((size_t)tau * BT + b) * HD + c8));
            }
        }
        __threadfence();
        __syncthreads();
        if (tid == 0)
            __hip_atomic_store(&flags[tile], 16u,
                               __ATOMIC_RELEASE, __HIP_MEMORY_SCOPE_AGENT);
        return;
    }

    // ================= CONSUMER: layer 1 + FC head =================
    float bias1[4];
    half8 wih1[4][4], whh1[4][4];
#pragma unroll
    for (int tI = 0; tI < 4; ++tI) {
        int g = tI * HD + wv * 16 + nn;
        bias1[tI] = bih1[g] + bhh1[g];
#pragma unroll
        for (int kk = 0; kk < 4; ++kk) {
            wih1[tI][kk] = ldw8(Wih1 + g * HD + kk * 32 + qd * 8);
            whh1[tI][kk] = ldw8(Whh1 + g * HD + kk * 32 + qd * 8);
        }
    }

    // zero h2 double buffer
    for (int i = tid * 8; i < 2 * SLOT; i += NTH * 8) *(half8*)&SM[B2C_OFF + i] = z8;

    // wait for producer chunk 0 (steps 0..7), then preload 4-step chunk 0
    if (tid == 0) {
        while (__hip_atomic_load(&flags[tile], __ATOMIC_ACQUIRE,
                                 __HIP_MEMORY_SCOPE_AGENT) < 1u)
            __builtin_amdgcn_s_sleep(2);
    }
    __syncthreads();
    __threadfence();   // every wave: acquire for its own subsequent loads
    {
#pragma unroll
        for (int k = 0; k < 2; ++k) {
            int e  = tid + k * NTH;     // 0..1023 b128-units
            int ti = e >> 8;
            int r  = e & 255;
            int b  = r >> 4;
            int c8 = (r & 15) * 8;
            half8 v = __builtin_nontemporal_load(
                (const half8*)(h1s + wsbase + ((size_t)ti * BT + b) * HD + c8));
            *(half8*)&SM[HBC_OFF + ti * SLOT + b * RS + c8] = v;
        }
    }

    float cs1[4] = {0.f, 0.f, 0.f, 0.f};

    half8 stg0 = z8, stg1 = z8;
    bool have = false;
    int sbuf = 0;

#pragma unroll 1
    for (int tau = 0; tau < TSTEPS; ++tau) {
        __syncthreads();

        if ((tau & 3) == 0 && tau + 4 < TSTEPS) {
            const int c = (tau >> 2) + 1;
            sbuf = c & 1;
            const unsigned need = (unsigned)((c + 2) >> 1);   // steps 4c..4c+3 <= 8*flag
            if (tid == 0) {
                while (__hip_atomic_load(&flags[tile], __ATOMIC_ACQUIRE,
                                         __HIP_MEMORY_SCOPE_AGENT) < need)
                    __builtin_amdgcn_s_sleep(2);
            }
            __syncthreads();
            __threadfence();
            // T14 split: issue nt loads now; LDS write after this iter's compute
            {
                int e0 = tid;       int ti0 = e0 >> 8, r0 = e0 & 255, b_0 = r0 >> 4, c80 = (r0 & 15) * 8;
                int e1 = tid + NTH; int ti1 = e1 >> 8, r1 = e1 & 255, b_1 = r1 >> 4, c81 = (r1 & 15) * 8;
                stg0 = __builtin_nontemporal_load(
                    (const half8*)(h1s + wsbase + ((size_t)(c * 4 + ti0) * BT + b_0) * HD + c80));
                stg1 = __builtin_nontemporal_load(
                    (const half8*)(h1s + wsbase + ((size_t)(c * 4 + ti1) * BT + b_1) * HD + c81));
            }
            have = true;
        }

        const int cur = tau & 1, nxt = cur ^ 1;
        const int hbase = HBC_OFF + ((tau >> 2) & 1) * (4 * SLOT) + (tau & 3) * SLOT;

        half8 a1[4], a2[4];
#pragma unroll
        for (int kk = 0; kk < 4; ++kk) {
            a1[kk] = *(const half8*)&SM[hbase + nn * RS + kk * 32 + qd * 8];
            a2[kk] = *(const half8*)&SM[B2C_OFF + cur * SLOT + nn * RS + kk * 32 + qd * 8];
        }

        floatx4 acc[4];
#pragma unroll
        for (int tI = 0; tI < 4; ++tI) {
            floatx4 a = {bias1[tI], bias1[tI], bias1[tI], bias1[tI]};
#pragma unroll
            for (int kk = 0; kk < 4; ++kk)
                a = __builtin_amdgcn_mfma_f32_16x16x32_f16(a1[kk], wih1[tI][kk], a, 0, 0, 0);
#pragma unroll
            for (int kk = 0; kk < 4; ++kk)
                a = __builtin_amdgcn_mfma_f32_16x16x32_f16(a2[kk], whh1[tI][kk], a, 0, 0, 0);
            acc[tI] = a;
        }

#pragma unroll
        for (int r = 0; r < 4; ++r) {
            float iv = sigf(acc[0][r]);
            float fv = sigf(acc[1][r]);
            float gv = tanh_f(acc[2][r]);
            float ov = sigf(acc[3][r]);
            float cn = fv * cs1[r] + iv * gv;
            cs1[r] = cn;
            SM[B2C_OFF + nxt * SLOT + (qd * 4 + r) * RS + jc] = (_Float16)(ov * tanh_f(cn));
        }

        if (have) {
            int e0 = tid;       int ti0 = e0 >> 8, r0 = e0 & 255, b_0 = r0 >> 4, c80 = (r0 & 15) * 8;
            int e1 = tid + NTH; int ti1 = e1 >> 8, r1 = e1 & 255, b_1 = r1 >> 4, c81 = (r1 & 15) * 8;
            *(half8*)&SM[HBC_OFF + sbuf * (4 * SLOT) + ti0 * SLOT + b_0 * RS + c80] = stg0;
            *(half8*)&SM[HBC_OFF + sbuf * (4 * SLOT) + ti1 * SLOT + b_1 * RS + c81] = stg1;
            have = false;
        }
    }
    __syncthreads();

    // FC head: h2[127] is in b2 slot 0 (written at tau=127 with nxt=0)
    {
        int b = tid >> 5, sub = tid & 31;
        const _Float16* hp = &SM[B2C_OFF + b * RS + sub * 4];
        const float4 wv4 = *(const float4*)(Wfc + sub * 4);
        float s = (float)hp[0] * wv4.x + (float)hp[1] * wv4.y
                + (float)hp[2] * wv4.z + (float)hp[3] * wv4.w;
        s += __shfl_down(s, 16, 32);
        s += __shfl_down(s, 8, 32);
        s += __shfl_down(s, 4, 32);
        s += __shfl_down(s, 2, 32);
        s += __shfl_down(s, 1, 32);
        if (sub == 0) out[b0 + b] = s + bfc[0];
    }
}

// =====================================================================
// Fallback: round-1 fused single-kernel version (verified, 311 us) —
// used only if ws_size cannot hold the h1 stream + flags.
// =====================================================================
#define H1B   (2*SLOT)
#define W1B   (4*SLOT)
#define FSM_ELTS (W1B + 8*16*512)
#define FSM_BYTES (FSM_ELTS*2)

__global__ __launch_bounds__(NTH, 2)
void lstm2_fused(const float* __restrict__ x,
                 const float* __restrict__ Wih0, const float* __restrict__ Whh0,
                 const float* __restrict__ bih0, const float* __restrict__ bhh0,
                 const float* __restrict__ Wih1, const float* __restrict__ Whh1,
                 const float* __restrict__ bih1, const float* __restrict__ bhh1,
                 const float* __restrict__ Wfc,  const float* __restrict__ bfc,
                 float* __restrict__ out)
{
    extern __shared__ __align__(16) _Float16 FSM[];

    const int tid = threadIdx.x;
    const int blk = blockIdx.x;
    const int wv  = tid >> 6;
    const int ln  = tid & 63;
    const int qd  = ln >> 4;
    const int nn  = ln & 15;
    const int b0  = blk * BT;
    const int jc  = wv * 16 + nn;

    const half8 z8 = {0, 0, 0, 0, 0, 0, 0, 0};

    for (int i = tid * 8; i < W1B; i += NTH * 8) *(half8*)&FSM[i] = z8;

    float bias0[4], bias1[4];
    half8 wih0[4];
    half8 whh0[4][4];
    half8 wih1[4][4];
#pragma unroll
    for (int tI = 0; tI < 4; ++tI) {
        int g = tI * HD + wv * 16 + nn;
        bias0[tI] = bih0[g] + bhh0[g];
        bias1[tI] = bih1[g] + bhh1[g];
        wih0[tI] = (qd < 3) ? ldw8(Wih0 + g * NIN + qd * 8) : z8;
#pragma unroll
        for (int kk = 0; kk < 4; ++kk) {
            whh0[tI][kk] = ldw8(Whh0 + g * HD + kk * 32 + qd * 8);
            wih1[tI][kk] = ldw8(Wih1 + g * HD + kk * 32 + qd * 8);
        }
    }

    for (int i = tid; i < 512 * 32; i += NTH) {
        int g  = i >> 5;
        int k0 = (i & 31) << 2;
        float4 v = *(const float4*)(Whh1 + g * HD + k0);
        half4v h; h[0] = (_Float16)v.x; h[1] = (_Float16)v.y;
                  h[2] = (_Float16)v.z; h[3] = (_Float16)v.w;
        int dst = W1B + ((((g >> 4) & 7) * 16) + (g >> 7) * 4 + (k0 >> 5)) * 512
                      + (((k0 >> 3) & 3) * 16 + (g & 15)) * 8 + (k0 & 7);
        *(half4v*)&FSM[dst] = h;
    }

    const float* xrow = x + (size_t)(b0 + nn) * (TSTEPS * NIN) + (qd < 3 ? qd * 8 : 16);
    float4 pf0 = *(const float4*)(xrow);
    float4 pf1 = *(const float4*)(xrow + 4);

    float cs0[4] = {0.f, 0.f, 0.f, 0.f};
    float cs1[4] = {0.f, 0.f, 0.f, 0.f};
    const int w1base = W1B + wv * 8192 + ln * 8;

    __syncthreads();

    {
        half8 ax;
        ax[0] = (_Float16)pf0.x; ax[1] = (_Float16)pf0.y; ax[2] = (_Float16)pf0.z; ax[3] = (_Float16)pf0.w;
        ax[4] = (_Float16)pf1.x; ax[5] = (_Float16)pf1.y; ax[6] = (_Float16)pf1.z; ax[7] = (_Float16)pf1.w;
        pf0 = *(const float4*)(xrow + NIN);
        pf1 = *(const float4*)(xrow + NIN + 4);

        floatx4 acc0[4];
#pragma unroll
        for (int tI = 0; tI < 4; ++tI) {
            floatx4 a0 = {bias0[tI], bias0[tI], bias0[tI], bias0[tI]};
            acc0[tI] = __builtin_amdgcn_mfma_f32_16x16x32_f16(ax, wih0[tI], a0, 0, 0, 0);
        }
#pragma unroll
        for (int r = 0; r < 4; ++r) {
            float iv = sigf(acc0[0][r]);
            float gv = tanh_f(acc0[2][r]);
            float ov = sigf(acc0[3][r]);
            float cn = iv * gv;
            cs0[r] = cn;
            FSM[(qd * 4 + r) * RS + jc] = (_Float16)(ov * tanh_f(cn));
        }
    }

#pragma unroll 1
    for (int t = 1; t < TSTEPS; ++t) {
        __syncthreads();

        half8 ax;
        ax[0] = (_Float16)pf0.x; ax[1] = (_Float16)pf0.y; ax[2] = (_Float16)pf0.z; ax[3] = (_Float16)pf0.w;
        ax[4] = (_Float16)pf1.x; ax[5] = (_Float16)pf1.y; ax[6] = (_Float16)pf1.z; ax[7] = (_Float16)pf1.w;
        {
            const int tn = (t < TSTEPS - 1) ? t + 1 : TSTEPS - 1;
            pf0 = *(const float4*)(xrow + tn * NIN);
            pf1 = *(const float4*)(xrow + tn * NIN + 4);
        }

        const int h0r = ((t - 1) & 1) * SLOT;
        const int h0w = (t & 1) * SLOT;
        const int h1r = H1B + (t & 1) * SLOT;
        const int h1w = H1B + ((t & 1) ^ 1) * SLOT;

        floatx4 acc0[4], acc1[4];
#pragma unroll
        for (int tI = 0; tI < 4; ++tI) {
            floatx4 a0 = {bias0[tI], bias0[tI], bias0[tI], bias0[tI]};
            acc0[tI] = __builtin_amdgcn_mfma_f32_16x16x32_f16(ax, wih0[tI], a0, 0, 0, 0);
            floatx4 a1 = {bias1[tI], bias1[tI], bias1[tI], bias1[tI]};
            acc1[tI] = a1;
        }

#pragma unroll
        for (int kk = 0; kk < 4; ++kk) {
            const half8 ah = *(const half8*)&FSM[h0r + nn * RS + kk * 32 + qd * 8];
#pragma unroll
            for (int tI = 0; tI < 4; ++tI)
                acc0[tI] = __builtin_amdgcn_mfma_f32_16x16x32_f16(ah, whh0[tI][kk], acc0[tI], 0, 0, 0);
#pragma unroll
            for (int tI = 0; tI < 4; ++tI)
                acc1[tI] = __builtin_amdgcn_mfma_f32_16x16x32_f16(ah, wih1[tI][kk], acc1[tI], 0, 0, 0);
        }

#pragma unroll
        for (int kk = 0; kk < 4; ++kk) {
            const half8 a2 = *(const half8*)&FSM[h1r + nn * RS + kk * 32 + qd * 8];
#pragma unroll
            for (int tI = 0; tI < 4; ++tI) {
                const half8 w1 = *(const half8*)&FSM[w1base + (tI * 4 + kk) * 512];
                acc1[tI] = __builtin_amdgcn_mfma_f32_16x16x32_f16(a2, w1, acc1[tI], 0, 0, 0);
            }
        }

#pragma unroll
        for (int r = 0; r < 4; ++r) {
            float iv = sigf(acc0[0][r]);
            float fv = sigf(acc0[1][r]);
            float gv = tanh_f(acc0[2][r]);
            float ov = sigf(acc0[3][r]);
            float cn = fv * cs0[r] + iv * gv;
            cs0[r] = cn;
            FSM[h0w + (qd * 4 + r) * RS + jc] = (_Float16)(ov * tanh_f(cn));
        }
#pragma unroll
        for (int r = 0; r < 4; ++r) {
            float iv = sigf(acc1[0][r]);
            float fv = sigf(acc1[1][r]);
            float gv = tanh_f(acc1[2][r]);
            float ov = sigf(acc1[3][r]);
            float cn = fv * cs1[r] + iv * gv;
            cs1[r] = cn;
            FSM[h1w + (qd * 4 + r) * RS + jc] = (_Float16)(ov * tanh_f(cn));
        }
    }

    {
        __syncthreads();
        floatx4 acc1[4];
#pragma unroll
        for (int tI = 0; tI < 4; ++tI) {
            floatx4 a1 = {bias1[tI], bias1[tI], bias1[tI], bias1[tI]};
            acc1[tI] = a1;
        }
#pragma unroll
        for (int kk = 0; kk < 4; ++kk) {
            const half8 ah = *(const half8*)&FSM[SLOT + nn * RS + kk * 32 + qd * 8];
#pragma unroll
            for (int tI = 0; tI < 4; ++tI)
                acc1[tI] = __builtin_amdgcn_mfma_f32_16x16x32_f16(ah, wih1[tI][kk], acc1[tI], 0, 0, 0);
        }
#pragma unroll
        for (int kk = 0; kk < 4; ++kk) {
            const half8 a2 = *(const half8*)&FSM[H1B + nn * RS + kk * 32 + qd * 8];
#pragma unroll
            for (int tI = 0; tI < 4; ++tI) {
                const half8 w1 = *(const half8*)&FSM[w1base + (tI * 4 + kk) * 512];
                acc1[tI] = __builtin_amdgcn_mfma_f32_16x16x32_f16(a2, w1, acc1[tI], 0, 0, 0);
            }
        }
#pragma unroll
        for (int r = 0; r < 4; ++r) {
            float iv = sigf(acc1[0][r]);
            float fv = sigf(acc1[1][r]);
            float gv = tanh_f(acc1[2][r]);
            float ov = sigf(acc1[3][r]);
            float cn = fv * cs1[r] + iv * gv;
            FSM[H1B + SLOT + (qd * 4 + r) * RS + jc] = (_Float16)(ov * tanh_f(cn));
        }
    }
    __syncthreads();

    {
        int b = tid >> 5, sub = tid & 31;
        const _Float16* hp = &FSM[H1B + SLOT + b * RS + sub * 4];
        const float4 wv4 = *(const float4*)(Wfc + sub * 4);
        float s = (float)hp[0] * wv4.x + (float)hp[1] * wv4.y
                + (float)hp[2] * wv4.z + (float)hp[3] * wv4.w;
        s += __shfl_down(s, 16, 32);
        s += __shfl_down(s, 8, 32);
        s += __shfl_down(s, 4, 32);
        s += __shfl_down(s, 2, 32);
        s += __shfl_down(s, 1, 32);
        if (sub == 0) out[b0 + b] = s + bfc[0];
    }
}

extern "C" void kernel_launch(void* const* d_in, const int* in_sizes, int n_in,
                              void* d_out, int out_size, void* d_ws, size_t ws_size,
                              hipStream_t stream) {
    static bool attr_set = false;
    if (!attr_set) {
        hipFuncSetAttribute(reinterpret_cast<const void*>(&lstm2_pipe),
                            hipFuncAttributeMaxDynamicSharedMemorySize, DYN_LDS);
        hipFuncSetAttribute(reinterpret_cast<const void*>(&lstm2_fused),
                            hipFuncAttributeMaxDynamicSharedMemorySize, FSM_BYTES);
        attr_set = true;
    }
    const float* x    = (const float*)d_in[0];
    const float* Wih0 = (const float*)d_in[1];
    const float* Whh0 = (const float*)d_in[2];
    const float* bih0 = (const float*)d_in[3];
    const float* bhh0 = (const float*)d_in[4];
    const float* Wih1 = (const float*)d_in[5];
    const float* Whh1 = (const float*)d_in[6];
    const float* bih1 = (const float*)d_in[7];
    const float* bhh1 = (const float*)d_in[8];
    const float* Wfc  = (const float*)d_in[9];
    const float* bfc  = (const float*)d_in[10];
    float* out = (float*)d_out;

    if (ws_size >= WS_NEED) {
        unsigned int* flags = (unsigned int*)d_ws;
        _Float16* h1s = (_Float16*)((char*)d_ws + WS_FLAGS_PAD);
        hipMemsetAsync(d_ws, 0, NTILE * sizeof(unsigned int), stream);
        lstm2_pipe<<<dim3(2 * NTILE), dim3(NTH), DYN_LDS, stream>>>(
            x, Wih0, Whh0, bih0, bhh0, Wih1, Whh1, bih1, bhh1, Wfc, bfc,
            out, h1s, flags);
    } else {
        lstm2_fused<<<dim3(NTILE), dim3(NTH), FSM_BYTES, stream>>>(
            x, Wih0, Whh0, bih0, bhh0, Wih1, Whh1, bih1, bhh1, Wfc, bfc, out);
    }
}

// Round 4
// 733.712 us; speedup vs baseline: 2.3994x; 2.3994x over previous
//
#include <hip/hip_runtime.h>

#define TSTEPS 128
#define NIN 24
#define HD 128
#define BT 16
#define NBLK 128     // 2048 / BT
#define NTH 512

// LDS geometry (units: _Float16 elements) — h panels only, no weight panel.
// Layout per panel: [batch 16][hidden 128] with row stride RS=136 (16B-aligned
// rows, 2-way bank alias only on both the b128 reads and b64 writes).
#define RS    136
#define SLOT  (BT*RS)          // 2176
#define H1B   (2*SLOT)         // layer-1 h double buffer after layer-0's
#define SM_ELTS (4*SLOT)       // 8704 f16 = 17408 B

typedef _Float16 half8  __attribute__((ext_vector_type(8)));
typedef _Float16 half4v __attribute__((ext_vector_type(4)));
typedef float    floatx4 __attribute__((ext_vector_type(4)));

__device__ __forceinline__ float sigf(float x) {
    return __builtin_amdgcn_rcpf(1.0f + __expf(-x));
}
__device__ __forceinline__ float tanh_f(float x) {
    return 1.0f - 2.0f * __builtin_amdgcn_rcpf(1.0f + __expf(2.0f * x));
}

__device__ __forceinline__ half8 ldw8(const float* p) {
    const float4* q = (const float4*)p;
    float4 a = q[0], b = q[1];
    half8 r;
    r[0] = (_Float16)a.x; r[1] = (_Float16)a.y; r[2] = (_Float16)a.z; r[3] = (_Float16)a.w;
    r[4] = (_Float16)b.x; r[5] = (_Float16)b.y; r[6] = (_Float16)b.z; r[7] = (_Float16)b.w;
    return r;
}

// =====================================================================
// Fused 2-layer LSTM, one block per 16-row batch tile.
// TRANSPOSED MFMA orientation: D = W · h^T (A = weight fragments, B = h
// fragments). A/B fragment layouts are lane-symmetric, so the register
// data is identical to the untransposed version — only the D mapping
// changes: lane (qd,nn) holds gate rows {tI*128 + wv*16 + qd*4 + r},
// batch col nn. Benefits:
//   - h-write is 4 CONTIGUOUS f16 -> one ds_write_b64 (was 4 scalar b16)
//   - bias becomes a per-lane floatx4 C-operand (AGPR-eligible)
// ALL four weight matrices live in the unified VGPR/AGPR file (MFMA
// reads A/B straight from AGPRs) — the W_hh1 LDS stream is gone.
// =====================================================================
__global__ __launch_bounds__(NTH, 2)
void lstm2_fused(const float* __restrict__ x,
                 const float* __restrict__ Wih0, const float* __restrict__ Whh0,
                 const float* __restrict__ bih0, const float* __restrict__ bhh0,
                 const float* __restrict__ Wih1, const float* __restrict__ Whh1,
                 const float* __restrict__ bih1, const float* __restrict__ bhh1,
                 const float* __restrict__ Wfc,  const float* __restrict__ bfc,
                 float* __restrict__ out)
{
    __shared__ __align__(16) _Float16 SM[SM_ELTS];

    const int tid = threadIdx.x;
    const int blk = blockIdx.x;
    const int wv  = tid >> 6;
    const int ln  = tid & 63;
    const int qd  = ln >> 4;
    const int nn  = ln & 15;
    const int b0  = blk * BT;
    const int hcol = wv * 16 + qd * 4;      // hidden col base this lane writes

    const half8 z8 = {0, 0, 0, 0, 0, 0, 0, 0};

    // ---- zero h0/h1 double buffers (state -1 reads as 0) ----
    for (int i = tid * 8; i < SM_ELTS; i += NTH * 8) *(half8*)&SM[i] = z8;

    // ---- biases as C-operand vectors: element r = gate row qd*4+r ----
    floatx4 bias0[4], bias1[4];
#pragma unroll
    for (int tI = 0; tI < 4; ++tI) {
#pragma unroll
        for (int r = 0; r < 4; ++r) {
            int g = tI * HD + hcol + r;
            bias0[tI][r] = bih0[g] + bhh0[g];
            bias1[tI][r] = bih1[g] + bhh1[g];
        }
    }

    // ---- weight fragments (A-operand): lane nn = gate row within tile ----
    half8 wih0[4];
    half8 whh0[4][4], wih1[4][4], whh1[4][4];
#pragma unroll
    for (int tI = 0; tI < 4; ++tI) {
        int g = tI * HD + wv * 16 + nn;
        wih0[tI] = (qd < 3) ? ldw8(Wih0 + g * NIN + qd * 8) : z8;
#pragma unroll
        for (int kk = 0; kk < 4; ++kk) {
            whh0[tI][kk] = ldw8(Whh0 + g * HD + kk * 32 + qd * 8);
            wih1[tI][kk] = ldw8(Wih1 + g * HD + kk * 32 + qd * 8);
            whh1[tI][kk] = ldw8(Whh1 + g * HD + kk * 32 + qd * 8);
        }
    }

    // ---- x register prefetch: lane supplies B-frag col nn (batch row),
    //      k = qd*8..+7; k>=24 multiplied by wih0==0, clamp the address ----
    const float* xrow = x + (size_t)(b0 + nn) * (TSTEPS * NIN) + (qd < 3 ? qd * 8 : 16);
    float4 pf0 = *(const float4*)(xrow);
    float4 pf1 = *(const float4*)(xrow + 4);

    float cs0[4] = {0.f, 0.f, 0.f, 0.f};
    float cs1[4] = {0.f, 0.f, 0.f, 0.f};

    __syncthreads();

    // =============== iter 0: layer0 step 0 (h0[-1]=0 -> only x MFMA) ===============
    {
        half8 ax;
        ax[0] = (_Float16)pf0.x; ax[1] = (_Float16)pf0.y; ax[2] = (_Float16)pf0.z; ax[3] = (_Float16)pf0.w;
        ax[4] = (_Float16)pf1.x; ax[5] = (_Float16)pf1.y; ax[6] = (_Float16)pf1.z; ax[7] = (_Float16)pf1.w;
        pf0 = *(const float4*)(xrow + NIN);
        pf1 = *(const float4*)(xrow + NIN + 4);

        floatx4 acc0[4];
#pragma unroll
        for (int tI = 0; tI < 4; ++tI)
            acc0[tI] = __builtin_amdgcn_mfma_f32_16x16x32_f16(wih0[tI], ax, bias0[tI], 0, 0, 0);

        half4v hw;
#pragma unroll
        for (int r = 0; r < 4; ++r) {
            float iv = sigf(acc0[0][r]);
            float gv = tanh_f(acc0[2][r]);
            float ov = sigf(acc0[3][r]);
            float cn = iv * gv;                    // c_prev = 0
            cs0[r] = cn;
            hw[r] = (_Float16)(ov * tanh_f(cn));
        }
        *(half4v*)&SM[0 * SLOT + nn * RS + hcol] = hw;   // h0[0] -> slot 0
    }

    // =============== main loop t = 1..127: layer0 step t + layer1 step t-1 ===============
#pragma unroll 1
    for (int t = 1; t < TSTEPS; ++t) {
        __syncthreads();   // h0[t-1], h1[t-2] visible

        half8 ax;
        ax[0] = (_Float16)pf0.x; ax[1] = (_Float16)pf0.y; ax[2] = (_Float16)pf0.z; ax[3] = (_Float16)pf0.w;
        ax[4] = (_Float16)pf1.x; ax[5] = (_Float16)pf1.y; ax[6] = (_Float16)pf1.z; ax[7] = (_Float16)pf1.w;
        {
            const int tn = (t < TSTEPS - 1) ? t + 1 : TSTEPS - 1;   // clamped re-load at t=127
            pf0 = *(const float4*)(xrow + tn * NIN);
            pf1 = *(const float4*)(xrow + tn * NIN + 4);
        }

        const int h0r = ((t - 1) & 1) * SLOT;
        const int h0w = (t & 1) * SLOT;
        const int h1r = H1B + (t & 1) * SLOT;            // h1[t-2]
        const int h1w = H1B + ((t & 1) ^ 1) * SLOT;      // h1[t-1]

        floatx4 acc0[4], acc1[4];
#pragma unroll
        for (int tI = 0; tI < 4; ++tI) {
            acc0[tI] = __builtin_amdgcn_mfma_f32_16x16x32_f16(wih0[tI], ax, bias0[tI], 0, 0, 0);
            acc1[tI] = bias1[tI];
        }

        __builtin_amdgcn_s_setprio(1);
        // h0[t-1] feeds BOTH layer0 recurrence and layer1 input: one read, 8 MFMAs
#pragma unroll
        for (int kk = 0; kk < 4; ++kk) {
            const half8 ah = *(const half8*)&SM[h0r + nn * RS + kk * 32 + qd * 8];
#pragma unroll
            for (int tI = 0; tI < 4; ++tI)
                acc0[tI] = __builtin_amdgcn_mfma_f32_16x16x32_f16(whh0[tI][kk], ah, acc0[tI], 0, 0, 0);
#pragma unroll
            for (int tI = 0; tI < 4; ++tI)
                acc1[tI] = __builtin_amdgcn_mfma_f32_16x16x32_f16(wih1[tI][kk], ah, acc1[tI], 0, 0, 0);
        }
        // layer1 recurrence: whh1 fragments straight from the register file
#pragma unroll
        for (int kk = 0; kk < 4; ++kk) {
            const half8 a2 = *(const half8*)&SM[h1r + nn * RS + kk * 32 + qd * 8];
#pragma unroll
            for (int tI = 0; tI < 4; ++tI)
                acc1[tI] = __builtin_amdgcn_mfma_f32_16x16x32_f16(whh1[tI][kk], a2, acc1[tI], 0, 0, 0);
        }
        __builtin_amdgcn_s_setprio(0);

        // elementwise layer0 -> h0[t]  (one contiguous b64 write)
        {
            half4v hw;
#pragma unroll
            for (int r = 0; r < 4; ++r) {
                float iv = sigf(acc0[0][r]);
                float fv = sigf(acc0[1][r]);
                float gv = tanh_f(acc0[2][r]);
                float ov = sigf(acc0[3][r]);
                float cn = fv * cs0[r] + iv * gv;
                cs0[r] = cn;
                hw[r] = (_Float16)(ov * tanh_f(cn));
            }
            *(half4v*)&SM[h0w + nn * RS + hcol] = hw;
        }
        // elementwise layer1 -> h1[t-1]
        {
            half4v hw;
#pragma unroll
            for (int r = 0; r < 4; ++r) {
                float iv = sigf(acc1[0][r]);
                float fv = sigf(acc1[1][r]);
                float gv = tanh_f(acc1[2][r]);
                float ov = sigf(acc1[3][r]);
                float cn = fv * cs1[r] + iv * gv;
                cs1[r] = cn;
                hw[r] = (_Float16)(ov * tanh_f(cn));
            }
            *(half4v*)&SM[h1w + nn * RS + hcol] = hw;
        }
    }

    // =============== iter 128: layer1 step 127 only ===============
    {
        __syncthreads();
        floatx4 acc1[4];
#pragma unroll
        for (int tI = 0; tI < 4; ++tI) acc1[tI] = bias1[tI];

#pragma unroll
        for (int kk = 0; kk < 4; ++kk) {
            const half8 ah = *(const half8*)&SM[SLOT + nn * RS + kk * 32 + qd * 8];   // h0[127] slot 1
#pragma unroll
            for (int tI = 0; tI < 4; ++tI)
                acc1[tI] = __builtin_amdgcn_mfma_f32_16x16x32_f16(wih1[tI][kk], ah, acc1[tI], 0, 0, 0);
        }
#pragma unroll
        for (int kk = 0; kk < 4; ++kk) {
            const half8 a2 = *(const half8*)&SM[H1B + nn * RS + kk * 32 + qd * 8];    // h1[126] slot 0
#pragma unroll
            for (int tI = 0; tI < 4; ++tI)
                acc1[tI] = __builtin_amdgcn_mfma_f32_16x16x32_f16(whh1[tI][kk], a2, acc1[tI], 0, 0, 0);
        }

        half4v hw;
#pragma unroll
        for (int r = 0; r < 4; ++r) {
            float iv = sigf(acc1[0][r]);
            float fv = sigf(acc1[1][r]);
            float gv = tanh_f(acc1[2][r]);
            float ov = sigf(acc1[3][r]);
            float cn = fv * cs1[r] + iv * gv;
            hw[r] = (_Float16)(ov * tanh_f(cn));
        }
        *(half4v*)&SM[H1B + SLOT + nn * RS + hcol] = hw;    // h1[127] -> slot 1
    }
    __syncthreads();

    // =============== FC head: h1[127] (layer-1 output) is in h1 slot 1 ===============
    {
        int b = tid >> 5, sub = tid & 31;
        const _Float16* hp = &SM[H1B + SLOT + b * RS + sub * 4];
        const float4 wv4 = *(const float4*)(Wfc + sub * 4);
        float s = (float)hp[0] * wv4.x + (float)hp[1] * wv4.y
                + (float)hp[2] * wv4.z + (float)hp[3] * wv4.w;
        s += __shfl_down(s, 16, 32);
        s += __shfl_down(s, 8, 32);
        s += __shfl_down(s, 4, 32);
        s += __shfl_down(s, 2, 32);
        s += __shfl_down(s, 1, 32);
        if (sub == 0) out[b0 + b] = s + bfc[0];
    }
}

extern "C" void kernel_launch(void* const* d_in, const int* in_sizes, int n_in,
                              void* d_out, int out_size, void* d_ws, size_t ws_size,
                              hipStream_t stream) {
    const float* x    = (const float*)d_in[0];
    const float* Wih0 = (const float*)d_in[1];
    const float* Whh0 = (const float*)d_in[2];
    const float* bih0 = (const float*)d_in[3];
    const float* bhh0 = (const float*)d_in[4];
    const float* Wih1 = (const float*)d_in[5];
    const float* Whh1 = (const float*)d_in[6];
    const float* bih1 = (const float*)d_in[7];
    const float* bhh1 = (const float*)d_in[8];
    const float* Wfc  = (const float*)d_in[9];
    const float* bfc  = (const float*)d_in[10];
    float* out = (float*)d_out;

    lstm2_fused<<<dim3(NBLK), dim3(NTH), 0, stream>>>(
        x, Wih0, Whh0, bih0, bhh0, Wih1, Whh1, bih1, bhh1, Wfc, bfc, out);
}

// Round 5
// 344.342 us; speedup vs baseline: 5.1126x; 2.1308x over previous
//
#include <hip/hip_runtime.h>

#define TSTEPS 128
#define NIN 24
#define HD 128
#define BT 16
#define NBLK 128     // 2048 / BT
#define NTH 512

// LDS geometry (units: _Float16 elements)
// h panels: [batch 16][hidden 128], row stride RS=136 (16B-aligned rows).
#define RS    136
#define SLOT  (BT*RS)          // 2176
#define H1B   (2*SLOT)         // h1 double buffer after h0's
#define W1B   (4*SLOT)         // whh1 fragment panel: 8 wv * 16 frags * 512
#define SM_ELTS (W1B + 65536)  // 74240 f16
#define SM_BYTES (SM_ELTS*2)   // 148480 B -> 1 block/CU (dynamic LDS)

// x pre-converted to f16, padded 24->32 with x[24]=1 (bias column), rest 0.
// layout: [b][t][32] f16
#define XH_ROW 32
#define XH_BYTES ((size_t)2048 * TSTEPS * XH_ROW * 2)   // 16.78 MB

typedef _Float16 half8  __attribute__((ext_vector_type(8)));
typedef _Float16 half4v __attribute__((ext_vector_type(4)));
typedef float    floatx4 __attribute__((ext_vector_type(4)));

__device__ __forceinline__ float sigf(float x) {
    return __builtin_amdgcn_rcpf(1.0f + __expf(-x));
}
__device__ __forceinline__ float tanh_f(float x) {
    return 1.0f - 2.0f * __builtin_amdgcn_rcpf(1.0f + __expf(2.0f * x));
}

__device__ __forceinline__ half8 ldw8(const float* p) {
    const float4* q = (const float4*)p;
    float4 a = q[0], b = q[1];
    half8 r;
    r[0] = (_Float16)a.x; r[1] = (_Float16)a.y; r[2] = (_Float16)a.z; r[3] = (_Float16)a.w;
    r[4] = (_Float16)b.x; r[5] = (_Float16)b.y; r[6] = (_Float16)b.z; r[7] = (_Float16)b.w;
    return r;
}

// LDS-only barrier: drain own ds ops, sync, do NOT drain vmcnt — global
// prefetch loads stay in flight across iterations (T4-style).
__device__ __forceinline__ void barrier_lgkm() {
    asm volatile("s_waitcnt lgkmcnt(0)" ::: "memory");
    __builtin_amdgcn_s_barrier();
    __builtin_amdgcn_sched_barrier(0);
}

// =====================================================================
// aux kernel: x f32 [2048][128][24] -> xh f16 [2048][128][32]
// (elements 0..23 = x, 24 = 1.0 for the bias fold, 25..31 = 0)
// =====================================================================
__global__ __launch_bounds__(256)
void xcvt(const float* __restrict__ x, _Float16* __restrict__ xh)
{
    int c = blockIdx.x * 256 + threadIdx.x;      // half8 chunk id
    if (c >= 2048 * TSTEPS * 4) return;
    int part = c & 3;
    size_t row = (size_t)(c >> 2);               // b*128 + t
    half8 v;
    if (part < 3) {
        v = ldw8(x + row * NIN + part * 8);
    } else {
        v = (half8){0, 0, 0, 0, 0, 0, 0, 0};
        v[0] = (_Float16)1.0f;
    }
    *(half8*)&xh[c * (size_t)8] = v;
}

// =====================================================================
// Fused 2-layer LSTM, one block per 16-row batch tile, one-lag fusion:
// iter t computes layer0 step t AND layer1 step t-1 (both consume
// h0[t-1]). Transposed MFMA orientation (A = weights, B = h^T): D maps
// lane (qd,nn) -> gate rows qd*4+r, batch col nn; h-write is one
// contiguous ds_write_b64. Weights in regs: wih0 (bias-folded via the
// constant-1 x column), whh0, wih1 (144 VGPRs). whh1 streams from a
// fragment-ordered LDS panel (keeping reg pressure under the 256/wave
// spill line — round 4 proved whh1-in-regs spills ~50 MB/launch).
// MODE 0: x from pre-converted f16 xh (one b128 load/iter).
// MODE 1: fallback, x f32 direct (ws too small).
// =====================================================================
template<int MODE>
__global__ __launch_bounds__(NTH, 2)
void lstm2_fused(const float* __restrict__ x,
                 const float* __restrict__ Wih0, const float* __restrict__ Whh0,
                 const float* __restrict__ bih0, const float* __restrict__ bhh0,
                 const float* __restrict__ Wih1, const float* __restrict__ Whh1,
                 const float* __restrict__ bih1, const float* __restrict__ bhh1,
                 const float* __restrict__ Wfc,  const float* __restrict__ bfc,
                 float* __restrict__ out, const _Float16* __restrict__ xh)
{
    extern __shared__ __align__(16) _Float16 SM[];

    const int tid = threadIdx.x;
    const int blk = blockIdx.x;
    const int wv  = tid >> 6;
    const int ln  = tid & 63;
    const int qd  = ln >> 4;
    const int nn  = ln & 15;
    const int b0  = blk * BT;
    const int hcol = wv * 16 + qd * 4;      // hidden col base this lane writes

    const half8 z8 = {0, 0, 0, 0, 0, 0, 0, 0};
    const floatx4 zf4 = {0.f, 0.f, 0.f, 0.f};

    // ---- zero h panels (state -1 reads as 0) ----
    for (int i = tid * 8; i < W1B; i += NTH * 8) *(half8*)&SM[i] = z8;

    // ---- layer-1 bias as C-operand vectors: element r = gate row qd*4+r ----
    floatx4 bias1[4];
#pragma unroll
    for (int tI = 0; tI < 4; ++tI)
#pragma unroll
        for (int r = 0; r < 4; ++r)
            bias1[tI][r] = bih1[tI * HD + hcol + r] + bhh1[tI * HD + hcol + r];

    // ---- register weights: wih0 (bias-folded), whh0, wih1 ----
    half8 wih0[4];
    half8 whh0[4][4], wih1[4][4];
#pragma unroll
    for (int tI = 0; tI < 4; ++tI) {
        int g = tI * HD + wv * 16 + nn;
        if (qd < 3) {
            wih0[tI] = ldw8(Wih0 + g * NIN + qd * 8);
        } else {
            wih0[tI] = z8;
            wih0[tI][0] = (_Float16)(bih0[g] + bhh0[g]);   // pairs with x[24]=1
        }
#pragma unroll
        for (int kk = 0; kk < 4; ++kk) {
            whh0[tI][kk] = ldw8(Whh0 + g * HD + kk * 32 + qd * 8);
            wih1[tI][kk] = ldw8(Wih1 + g * HD + kk * 32 + qd * 8);
        }
    }

    // ---- stage whh1 -> LDS in MFMA A-fragment order ----
    // frag (wv_,tI_,kk_): element (qd_,nn_,e) at frag*512 + (qd_*16+nn_)*8 + e
    for (int i = tid; i < 512 * 32; i += NTH) {
        int g  = i >> 5;
        int k0 = (i & 31) << 2;
        float4 v = *(const float4*)(Whh1 + g * HD + k0);
        half4v h; h[0] = (_Float16)v.x; h[1] = (_Float16)v.y;
                  h[2] = (_Float16)v.z; h[3] = (_Float16)v.w;
        int dst = W1B + ((((g >> 4) & 7) * 16) + (g >> 7) * 4 + (k0 >> 5)) * 512
                      + (((k0 >> 3) & 3) * 16 + (g & 15)) * 8 + (k0 & 7);
        *(half4v*)&SM[dst] = h;
    }
    const int w1base = W1B + wv * 8192 + ln * 8;

    // ---- x access setup + first prefetch ----
    const _Float16* xbase = nullptr;
    const float*    xrow  = nullptr;
    half8 ax, axn;
    float4 pf0, pf1;
    if constexpr (MODE == 0) {
        xbase = xh + ((size_t)(b0 + nn) * TSTEPS) * XH_ROW + qd * 8;
        ax = *(const half8*)(xbase);                 // t = 0
    } else {
        xrow = x + (size_t)(b0 + nn) * (TSTEPS * NIN) + (qd < 3 ? qd * 8 : 0);
        pf0 = *(const float4*)(xrow);
        pf1 = *(const float4*)(xrow + 4);
    }

    float cs0[4] = {0.f, 0.f, 0.f, 0.f};
    float cs1[4] = {0.f, 0.f, 0.f, 0.f};

    __syncthreads();   // zeros + whh1 panel + (vmcnt drained once, pre-loop)

    // =============== iter 0: layer0 step 0 (h0[-1]=0 -> only x MFMA) ===============
    {
        if constexpr (MODE == 1) {
            if (qd < 3) {
                ax = z8;
                ax[0] = (_Float16)pf0.x; ax[1] = (_Float16)pf0.y; ax[2] = (_Float16)pf0.z; ax[3] = (_Float16)pf0.w;
                ax[4] = (_Float16)pf1.x; ax[5] = (_Float16)pf1.y; ax[6] = (_Float16)pf1.z; ax[7] = (_Float16)pf1.w;
            } else {
                ax = z8; ax[0] = (_Float16)1.0f;
            }
            pf0 = *(const float4*)(xrow + NIN);
            pf1 = *(const float4*)(xrow + NIN + 4);
        } else {
            axn = *(const half8*)(xbase + XH_ROW);   // t = 1
        }

        floatx4 acc0[4];
#pragma unroll
        for (int tI = 0; tI < 4; ++tI)
            acc0[tI] = __builtin_amdgcn_mfma_f32_16x16x32_f16(wih0[tI], ax, zf4, 0, 0, 0);

        half4v hw;
#pragma unroll
        for (int r = 0; r < 4; ++r) {
            float iv = sigf(acc0[0][r]);
            float gv = tanh_f(acc0[2][r]);
            float ov = sigf(acc0[3][r]);
            float cn = iv * gv;                    // c_prev = 0
            cs0[r] = cn;
            hw[r] = (_Float16)(ov * tanh_f(cn));
        }
        *(half4v*)&SM[0 * SLOT + nn * RS + hcol] = hw;   // h0[0] -> slot 0
        if constexpr (MODE == 0) ax = axn;
    }

    // =============== main loop t = 1..127: layer0 step t + layer1 step t-1 ===============
#pragma unroll 1
    for (int t = 1; t < TSTEPS; ++t) {
        barrier_lgkm();   // h0[t-1], h1[t-2] visible; vmcnt NOT drained

        // prefetch x for t+1 (issued early; spans the barrier)
        if constexpr (MODE == 0) {
            const int tn = (t < TSTEPS - 1) ? t + 1 : TSTEPS - 1;
            axn = *(const half8*)(xbase + (size_t)tn * XH_ROW);
        } else {
            if (qd < 3) {
                ax = z8;
                ax[0] = (_Float16)pf0.x; ax[1] = (_Float16)pf0.y; ax[2] = (_Float16)pf0.z; ax[3] = (_Float16)pf0.w;
                ax[4] = (_Float16)pf1.x; ax[5] = (_Float16)pf1.y; ax[6] = (_Float16)pf1.z; ax[7] = (_Float16)pf1.w;
            } else {
                ax = z8; ax[0] = (_Float16)1.0f;
            }
            const int tn = (t < TSTEPS - 1) ? t + 1 : TSTEPS - 1;
            pf0 = *(const float4*)(xrow + (size_t)tn * NIN);
            pf1 = *(const float4*)(xrow + (size_t)tn * NIN + 4);
        }

        const int h0r = ((t - 1) & 1) * SLOT;
        const int h0w = (t & 1) * SLOT;
        const int h1r = H1B + (t & 1) * SLOT;            // h1[t-2]
        const int h1w = H1B + ((t & 1) ^ 1) * SLOT;      // h1[t-1]

        floatx4 acc0[4], acc1[4];
#pragma unroll
        for (int tI = 0; tI < 4; ++tI) {
            acc0[tI] = __builtin_amdgcn_mfma_f32_16x16x32_f16(wih0[tI], ax, zf4, 0, 0, 0);
            acc1[tI] = bias1[tI];
        }

        __builtin_amdgcn_s_setprio(1);
        // h0[t-1] feeds BOTH layer0 recurrence and layer1 input
#pragma unroll
        for (int kk = 0; kk < 4; ++kk) {
            const half8 ah = *(const half8*)&SM[h0r + nn * RS + kk * 32 + qd * 8];
#pragma unroll
            for (int tI = 0; tI < 4; ++tI)
                acc0[tI] = __builtin_amdgcn_mfma_f32_16x16x32_f16(whh0[tI][kk], ah, acc0[tI], 0, 0, 0);
#pragma unroll
            for (int tI = 0; tI < 4; ++tI)
                acc1[tI] = __builtin_amdgcn_mfma_f32_16x16x32_f16(wih1[tI][kk], ah, acc1[tI], 0, 0, 0);
        }
        // layer1 recurrence: whh1 fragments streamed from LDS panel
#pragma unroll
        for (int kk = 0; kk < 4; ++kk) {
            const half8 a2 = *(const half8*)&SM[h1r + nn * RS + kk * 32 + qd * 8];
#pragma unroll
            for (int tI = 0; tI < 4; ++tI) {
                const half8 w1 = *(const half8*)&SM[w1base + (tI * 4 + kk) * 512];
                acc1[tI] = __builtin_amdgcn_mfma_f32_16x16x32_f16(w1, a2, acc1[tI], 0, 0, 0);
            }
        }
        __builtin_amdgcn_s_setprio(0);

        // elementwise layer0 -> h0[t]  (one contiguous b64 write)
        {
            half4v hw;
#pragma unroll
            for (int r = 0; r < 4; ++r) {
                float iv = sigf(acc0[0][r]);
                float fv = sigf(acc0[1][r]);
                float gv = tanh_f(acc0[2][r]);
                float ov = sigf(acc0[3][r]);
                float cn = fv * cs0[r] + iv * gv;
                cs0[r] = cn;
                hw[r] = (_Float16)(ov * tanh_f(cn));
            }
            *(half4v*)&SM[h0w + nn * RS + hcol] = hw;
        }
        // elementwise layer1 -> h1[t-1]
        {
            half4v hw;
#pragma unroll
            for (int r = 0; r < 4; ++r) {
                float iv = sigf(acc1[0][r]);
                float fv = sigf(acc1[1][r]);
                float gv = tanh_f(acc1[2][r]);
                float ov = sigf(acc1[3][r]);
                float cn = fv * cs1[r] + iv * gv;
                cs1[r] = cn;
                hw[r] = (_Float16)(ov * tanh_f(cn));
            }
            *(half4v*)&SM[h1w + nn * RS + hcol] = hw;
        }
        if constexpr (MODE == 0) ax = axn;
    }

    // =============== iter 128: layer1 step 127 only ===============
    {
        barrier_lgkm();
        floatx4 acc1[4];
#pragma unroll
        for (int tI = 0; tI < 4; ++tI) acc1[tI] = bias1[tI];

#pragma unroll
        for (int kk = 0; kk < 4; ++kk) {
            const half8 ah = *(const half8*)&SM[SLOT + nn * RS + kk * 32 + qd * 8];   // h0[127] slot 1
#pragma unroll
            for (int tI = 0; tI < 4; ++tI)
                acc1[tI] = __builtin_amdgcn_mfma_f32_16x16x32_f16(wih1[tI][kk], ah, acc1[tI], 0, 0, 0);
        }
#pragma unroll
        for (int kk = 0; kk < 4; ++kk) {
            const half8 a2 = *(const half8*)&SM[H1B + nn * RS + kk * 32 + qd * 8];    // h1[126] slot 0
#pragma unroll
            for (int tI = 0; tI < 4; ++tI) {
                const half8 w1 = *(const half8*)&SM[w1base + (tI * 4 + kk) * 512];
                acc1[tI] = __builtin_amdgcn_mfma_f32_16x16x32_f16(w1, a2, acc1[tI], 0, 0, 0);
            }
        }

        half4v hw;
#pragma unroll
        for (int r = 0; r < 4; ++r) {
            float iv = sigf(acc1[0][r]);
            float fv = sigf(acc1[1][r]);
            float gv = tanh_f(acc1[2][r]);
            float ov = sigf(acc1[3][r]);
            float cn = fv * cs1[r] + iv * gv;
            hw[r] = (_Float16)(ov * tanh_f(cn));
        }
        *(half4v*)&SM[H1B + SLOT + nn * RS + hcol] = hw;    // h1[127] -> slot 1
    }
    barrier_lgkm();

    // =============== FC head: h1[127] is in h1 slot 1 ===============
    {
        int b = tid >> 5, sub = tid & 31;
        const _Float16* hp = &SM[H1B + SLOT + b * RS + sub * 4];
        const float4 wv4 = *(const float4*)(Wfc + sub * 4);
        float s = (float)hp[0] * wv4.x + (float)hp[1] * wv4.y
                + (float)hp[2] * wv4.z + (float)hp[3] * wv4.w;
        s += __shfl_down(s, 16, 32);
        s += __shfl_down(s, 8, 32);
        s += __shfl_down(s, 4, 32);
        s += __shfl_down(s, 2, 32);
        s += __shfl_down(s, 1, 32);
        if (sub == 0) out[b0 + b] = s + bfc[0];
    }
}

extern "C" void kernel_launch(void* const* d_in, const int* in_sizes, int n_in,
                              void* d_out, int out_size, void* d_ws, size_t ws_size,
                              hipStream_t stream) {
    static bool attr_set = false;
    if (!attr_set) {
        hipFuncSetAttribute(reinterpret_cast<const void*>(&lstm2_fused<0>),
                            hipFuncAttributeMaxDynamicSharedMemorySize, SM_BYTES);
        hipFuncSetAttribute(reinterpret_cast<const void*>(&lstm2_fused<1>),
                            hipFuncAttributeMaxDynamicSharedMemorySize, SM_BYTES);
        attr_set = true;
    }
    const float* x    = (const float*)d_in[0];
    const float* Wih0 = (const float*)d_in[1];
    const float* Whh0 = (const float*)d_in[2];
    const float* bih0 = (const float*)d_in[3];
    const float* bhh0 = (const float*)d_in[4];
    const float* Wih1 = (const float*)d_in[5];
    const float* Whh1 = (const float*)d_in[6];
    const float* bih1 = (const float*)d_in[7];
    const float* bhh1 = (const float*)d_in[8];
    const float* Wfc  = (const float*)d_in[9];
    const float* bfc  = (const float*)d_in[10];
    float* out = (float*)d_out;

    if (ws_size >= XH_BYTES) {
        _Float16* xhp = (_Float16*)d_ws;
        xcvt<<<dim3((2048 * TSTEPS * 4 + 255) / 256), dim3(256), 0, stream>>>(x, xhp);
        lstm2_fused<0><<<dim3(NBLK), dim3(NTH), SM_BYTES, stream>>>(
            x, Wih0, Whh0, bih0, bhh0, Wih1, Whh1, bih1, bhh1, Wfc, bfc, out, xhp);
    } else {
        lstm2_fused<1><<<dim3(NBLK), dim3(NTH), SM_BYTES, stream>>>(
            x, Wih0, Whh0, bih0, bhh0, Wih1, Whh1, bih1, bhh1, Wfc, bfc, out, nullptr);
    }
}

// Round 6
// 319.174 us; speedup vs baseline: 5.5157x; 1.0789x over previous
//
#include <hip/hip_runtime.h>

#define TSTEPS 128
#define NIN 24
#define HD 128
#define BT 16
#define NBLK 128     // 2048 / BT
#define NTH 1024     // 16 waves: 0-7 = layer-0 role, 8-15 = layer-1 role

// LDS geometry (units: _Float16 elements)
// h panels: [batch 16][hidden 128], row stride RS=136 (16B-aligned rows).
#define RS    136
#define SLOT  (BT*RS)          // 2176
#define H1B   (2*SLOT)         // h1 double buffer after h0's
#define W1B   (4*SLOT)         // whh1 fragment panel: 8 groups * 16 frags * 512
#define SM_ELTS (W1B + 65536)  // 74240 f16
#define SM_BYTES (SM_ELTS*2)   // 148480 B (dynamic LDS, 1 block/CU)

typedef _Float16 half8  __attribute__((ext_vector_type(8)));
typedef _Float16 half4v __attribute__((ext_vector_type(4)));
typedef float    floatx4 __attribute__((ext_vector_type(4)));

__device__ __forceinline__ float sigf(float x) {
    return __builtin_amdgcn_rcpf(1.0f + __expf(-x));
}
__device__ __forceinline__ float tanh_f(float x) {
    return 1.0f - 2.0f * __builtin_amdgcn_rcpf(1.0f + __expf(2.0f * x));
}

__device__ __forceinline__ half8 ldw8(const float* p) {
    const float4* q = (const float4*)p;
    float4 a = q[0], b = q[1];
    half8 r;
    r[0] = (_Float16)a.x; r[1] = (_Float16)a.y; r[2] = (_Float16)a.z; r[3] = (_Float16)a.w;
    r[4] = (_Float16)b.x; r[5] = (_Float16)b.y; r[6] = (_Float16)b.z; r[7] = (_Float16)b.w;
    return r;
}

// LDS-only barrier: drain own ds ops, sync, don't drain vmcnt (global x
// prefetch loads span barriers, T4-style).
__device__ __forceinline__ void barrier_lgkm() {
    asm volatile("s_waitcnt lgkmcnt(0)" ::: "memory");
    __builtin_amdgcn_s_barrier();
    __builtin_amdgcn_sched_barrier(0);
}

// =====================================================================
// Fused 2-layer LSTM, one block per 16-row batch tile, WAVE-ROLE SPLIT:
//   waves 0-7  : layer 0, hidden group wv     (wih0+whh0 in regs, ~118 VGPR)
//   waves 8-15 : layer 1, hidden group wv-8   (wih1 in regs, whh1 via the
//                LDS fragment panel, ~110 VGPR)
// 16 waves @ <=128 VGPR -> 4 waves/SIMD (2 L0 + 2 L1 per SIMD): the two
// roles have different pipe mixes, so LDS / MFMA / trans-VALU overlap
// across waves instead of lockstep phase convergence (round-5's limit).
// One-lag fusion: iteration t computes layer0 step t and layer1 step t-1,
// both consuming h0[t-1]; one barrier per iteration, by arrival count
// (both roles execute exactly 130 barriers).
// Transposed MFMA orientation throughout (A=weights, B=h^T): lane (qd,nn)
// holds gate rows hw*16+qd*4+r, batch col nn; h-write is one ds_write_b64.
// Layer-0 bias folded into the x-MFMA via a constant-1 x column.
// =====================================================================
__global__ __launch_bounds__(NTH, 4)
void lstm2_fused(const float* __restrict__ x,
                 const float* __restrict__ Wih0, const float* __restrict__ Whh0,
                 const float* __restrict__ bih0, const float* __restrict__ bhh0,
                 const float* __restrict__ Wih1, const float* __restrict__ Whh1,
                 const float* __restrict__ bih1, const float* __restrict__ bhh1,
                 const float* __restrict__ Wfc,  const float* __restrict__ bfc,
                 float* __restrict__ out)
{
    extern __shared__ __align__(16) _Float16 SM[];

    const int tid = threadIdx.x;
    const int blk = blockIdx.x;
    const int wv  = tid >> 6;
    const int ln  = tid & 63;
    const int qd  = ln >> 4;
    const int nn  = ln & 15;
    const int b0  = blk * BT;

    const half8 z8 = {0, 0, 0, 0, 0, 0, 0, 0};
    const floatx4 zf4 = {0.f, 0.f, 0.f, 0.f};

    // ---- common prologue: zero h panels, stage whh1 panel (all 16 waves) ----
    for (int i = tid * 8; i < W1B; i += NTH * 8) *(half8*)&SM[i] = z8;
    // whh1 -> LDS in MFMA A-fragment order (refcheck'd in rounds 1/5):
    // frag (hw_,tI,kk) at W1B + (hw_*16 + tI*4 + kk)*512 + (qd*16+nn)*8 + e
    for (int i = tid; i < 512 * 32; i += NTH) {
        int g  = i >> 5;
        int k0 = (i & 31) << 2;
        float4 v = *(const float4*)(Whh1 + g * HD + k0);
        half4v h; h[0] = (_Float16)v.x; h[1] = (_Float16)v.y;
                  h[2] = (_Float16)v.z; h[3] = (_Float16)v.w;
        int dst = W1B + ((((g >> 4) & 7) * 16) + (g >> 7) * 4 + (k0 >> 5)) * 512
                      + (((k0 >> 3) & 3) * 16 + (g & 15)) * 8 + (k0 & 7);
        *(half4v*)&SM[dst] = h;
    }

    if (wv < 8) {
        // ================= ROLE L0: layer 0, hidden cols wv*16..+16 =================
        const int hw_  = wv;
        const int hcol = hw_ * 16 + qd * 4;

        half8 wih0[4];           // bias folded at qd==3 via constant-1 x col
        half8 whh0[4][4];
#pragma unroll
        for (int tI = 0; tI < 4; ++tI) {
            int g = tI * HD + hw_ * 16 + nn;
            if (qd < 3) {
                wih0[tI] = ldw8(Wih0 + g * NIN + qd * 8);
            } else {
                wih0[tI] = z8;
                wih0[tI][0] = (_Float16)(bih0[g] + bhh0[g]);
            }
#pragma unroll
            for (int kk = 0; kk < 4; ++kk)
                whh0[tI][kk] = ldw8(Whh0 + g * HD + kk * 32 + qd * 8);
        }

        // x direct f32 (no aux conversion kernel): lane supplies B-frag col nn,
        // k = qd*8..+7; qd==3 -> constant {1,0,...} pairing with the bias frag.
        const float* xrow = x + (size_t)(b0 + nn) * (TSTEPS * NIN) + (qd < 3 ? qd * 8 : 0);
        float4 pf0 = *(const float4*)(xrow);
        float4 pf1 = *(const float4*)(xrow + 4);

        float cs0[4] = {0.f, 0.f, 0.f, 0.f};

        __syncthreads();   // barrier #0: zeros + whh1 panel staged

        // ---- iter 0: h0[0] (h0[-1]=0 -> only x MFMA) ----
        {
            half8 ax;
            if (qd < 3) {
                ax[0] = (_Float16)pf0.x; ax[1] = (_Float16)pf0.y; ax[2] = (_Float16)pf0.z; ax[3] = (_Float16)pf0.w;
                ax[4] = (_Float16)pf1.x; ax[5] = (_Float16)pf1.y; ax[6] = (_Float16)pf1.z; ax[7] = (_Float16)pf1.w;
            } else {
                ax = z8; ax[0] = (_Float16)1.0f;
            }
            pf0 = *(const float4*)(xrow + NIN);
            pf1 = *(const float4*)(xrow + NIN + 4);

            floatx4 acc0[4];
#pragma unroll
            for (int tI = 0; tI < 4; ++tI)
                acc0[tI] = __builtin_amdgcn_mfma_f32_16x16x32_f16(wih0[tI], ax, zf4, 0, 0, 0);

            half4v hw;
#pragma unroll
            for (int r = 0; r < 4; ++r) {
                float iv = sigf(acc0[0][r]);
                float gv = tanh_f(acc0[2][r]);
                float ov = sigf(acc0[3][r]);
                float cn = iv * gv;
                cs0[r] = cn;
                hw[r] = (_Float16)(ov * tanh_f(cn));
            }
            *(half4v*)&SM[0 * SLOT + nn * RS + hcol] = hw;   // h0[0] -> slot 0
        }

#pragma unroll 1
        for (int t = 1; t < TSTEPS; ++t) {
            barrier_lgkm();   // barrier #t

            half8 ax;
            if (qd < 3) {
                ax[0] = (_Float16)pf0.x; ax[1] = (_Float16)pf0.y; ax[2] = (_Float16)pf0.z; ax[3] = (_Float16)pf0.w;
                ax[4] = (_Float16)pf1.x; ax[5] = (_Float16)pf1.y; ax[6] = (_Float16)pf1.z; ax[7] = (_Float16)pf1.w;
            } else {
                ax = z8; ax[0] = (_Float16)1.0f;
            }
            {
                const int tn = (t < TSTEPS - 1) ? t + 1 : TSTEPS - 1;
                pf0 = *(const float4*)(xrow + (size_t)tn * NIN);
                pf1 = *(const float4*)(xrow + (size_t)tn * NIN + 4);
            }

            const int h0r = ((t - 1) & 1) * SLOT;
            const int h0w = (t & 1) * SLOT;

            floatx4 acc0[4];
#pragma unroll
            for (int tI = 0; tI < 4; ++tI)
                acc0[tI] = __builtin_amdgcn_mfma_f32_16x16x32_f16(wih0[tI], ax, zf4, 0, 0, 0);

            __builtin_amdgcn_s_setprio(1);
#pragma unroll
            for (int kk = 0; kk < 4; ++kk) {
                const half8 ah = *(const half8*)&SM[h0r + nn * RS + kk * 32 + qd * 8];
#pragma unroll
                for (int tI = 0; tI < 4; ++tI)
                    acc0[tI] = __builtin_amdgcn_mfma_f32_16x16x32_f16(whh0[tI][kk], ah, acc0[tI], 0, 0, 0);
            }
            __builtin_amdgcn_s_setprio(0);

            half4v hw;
#pragma unroll
            for (int r = 0; r < 4; ++r) {
                float iv = sigf(acc0[0][r]);
                float fv = sigf(acc0[1][r]);
                float gv = tanh_f(acc0[2][r]);
                float ov = sigf(acc0[3][r]);
                float cn = fv * cs0[r] + iv * gv;
                cs0[r] = cn;
                hw[r] = (_Float16)(ov * tanh_f(cn));
            }
            *(half4v*)&SM[h0w + nn * RS + hcol] = hw;
        }

        barrier_lgkm();   // barrier #128 (publishes h0[127])
        barrier_lgkm();   // barrier #129 (waits for L1's h1[127])
    } else {
        // ================= ROLE L1: layer 1, hidden cols (wv-8)*16..+16 =================
        const int hw_  = wv - 8;
        const int hcol = hw_ * 16 + qd * 4;

        floatx4 bias1[4];
        half8 wih1[4][4];
#pragma unroll
        for (int tI = 0; tI < 4; ++tI) {
#pragma unroll
            for (int r = 0; r < 4; ++r)
                bias1[tI][r] = bih1[tI * HD + hcol + r] + bhh1[tI * HD + hcol + r];
            int g = tI * HD + hw_ * 16 + nn;
#pragma unroll
            for (int kk = 0; kk < 4; ++kk)
                wih1[tI][kk] = ldw8(Wih1 + g * HD + kk * 32 + qd * 8);
        }
        const int w1base = W1B + hw_ * 8192 + ln * 8;

        float cs1[4] = {0.f, 0.f, 0.f, 0.f};

        __syncthreads();   // barrier #0

        // loop t = 1..127 computes h1[t-1]
#pragma unroll 1
        for (int t = 1; t < TSTEPS; ++t) {
            barrier_lgkm();   // barrier #t: h0[t-1], h1[t-2] visible

            const int h0r = ((t - 1) & 1) * SLOT;
            const int h1r = H1B + (t & 1) * SLOT;            // h1[t-2]
            const int h1w = H1B + ((t & 1) ^ 1) * SLOT;      // h1[t-1]

            floatx4 acc1[4];
#pragma unroll
            for (int tI = 0; tI < 4; ++tI) acc1[tI] = bias1[tI];

            __builtin_amdgcn_s_setprio(1);
#pragma unroll
            for (int kk = 0; kk < 4; ++kk) {
                const half8 ah = *(const half8*)&SM[h0r + nn * RS + kk * 32 + qd * 8];
#pragma unroll
                for (int tI = 0; tI < 4; ++tI)
                    acc1[tI] = __builtin_amdgcn_mfma_f32_16x16x32_f16(wih1[tI][kk], ah, acc1[tI], 0, 0, 0);
            }
#pragma unroll
            for (int kk = 0; kk < 4; ++kk) {
                const half8 a2 = *(const half8*)&SM[h1r + nn * RS + kk * 32 + qd * 8];
#pragma unroll
                for (int tI = 0; tI < 4; ++tI) {
                    const half8 w1 = *(const half8*)&SM[w1base + (tI * 4 + kk) * 512];
                    acc1[tI] = __builtin_amdgcn_mfma_f32_16x16x32_f16(w1, a2, acc1[tI], 0, 0, 0);
                }
            }
            __builtin_amdgcn_s_setprio(0);

            half4v hw;
#pragma unroll
            for (int r = 0; r < 4; ++r) {
                float iv = sigf(acc1[0][r]);
                float fv = sigf(acc1[1][r]);
                float gv = tanh_f(acc1[2][r]);
                float ov = sigf(acc1[3][r]);
                float cn = fv * cs1[r] + iv * gv;
                cs1[r] = cn;
                hw[r] = (_Float16)(ov * tanh_f(cn));
            }
            *(half4v*)&SM[h1w + nn * RS + hcol] = hw;
        }

        barrier_lgkm();   // barrier #128: h0[127] visible
        {
            // ---- epilogue: h1[127] from h0[127] (slot 1) + h1[126] (slot 0) ----
            floatx4 acc1[4];
#pragma unroll
            for (int tI = 0; tI < 4; ++tI) acc1[tI] = bias1[tI];
#pragma unroll
            for (int kk = 0; kk < 4; ++kk) {
                const half8 ah = *(const half8*)&SM[SLOT + nn * RS + kk * 32 + qd * 8];
#pragma unroll
                for (int tI = 0; tI < 4; ++tI)
                    acc1[tI] = __builtin_amdgcn_mfma_f32_16x16x32_f16(wih1[tI][kk], ah, acc1[tI], 0, 0, 0);
            }
#pragma unroll
            for (int kk = 0; kk < 4; ++kk) {
                const half8 a2 = *(const half8*)&SM[H1B + nn * RS + kk * 32 + qd * 8];
#pragma unroll
                for (int tI = 0; tI < 4; ++tI) {
                    const half8 w1 = *(const half8*)&SM[w1base + (tI * 4 + kk) * 512];
                    acc1[tI] = __builtin_amdgcn_mfma_f32_16x16x32_f16(w1, a2, acc1[tI], 0, 0, 0);
                }
            }
            half4v hw;
#pragma unroll
            for (int r = 0; r < 4; ++r) {
                float iv = sigf(acc1[0][r]);
                float fv = sigf(acc1[1][r]);
                float gv = tanh_f(acc1[2][r]);
                float ov = sigf(acc1[3][r]);
                float cn = fv * cs1[r] + iv * gv;
                hw[r] = (_Float16)(ov * tanh_f(cn));
            }
            *(half4v*)&SM[H1B + SLOT + nn * RS + hcol] = hw;   // h1[127] -> slot 1
        }
        barrier_lgkm();   // barrier #129: publish h1[127]
    }

    // =============== FC head: h1[127] in h1 slot 1 (first 512 threads) ===============
    if (tid < 512) {
        int b = tid >> 5, sub = tid & 31;
        const _Float16* hp = &SM[H1B + SLOT + b * RS + sub * 4];
        const float4 wv4 = *(const float4*)(Wfc + sub * 4);
        float s = (float)hp[0] * wv4.x + (float)hp[1] * wv4.y
                + (float)hp[2] * wv4.z + (float)hp[3] * wv4.w;
        s += __shfl_down(s, 16, 32);
        s += __shfl_down(s, 8, 32);
        s += __shfl_down(s, 4, 32);
        s += __shfl_down(s, 2, 32);
        s += __shfl_down(s, 1, 32);
        if (sub == 0) out[b0 + b] = s + bfc[0];
    }
}

extern "C" void kernel_launch(void* const* d_in, const int* in_sizes, int n_in,
                              void* d_out, int out_size, void* d_ws, size_t ws_size,
                              hipStream_t stream) {
    static bool attr_set = false;
    if (!attr_set) {
        hipFuncSetAttribute(reinterpret_cast<const void*>(&lstm2_fused),
                            hipFuncAttributeMaxDynamicSharedMemorySize, SM_BYTES);
        attr_set = true;
    }
    const float* x    = (const float*)d_in[0];
    const float* Wih0 = (const float*)d_in[1];
    const float* Whh0 = (const float*)d_in[2];
    const float* bih0 = (const float*)d_in[3];
    const float* bhh0 = (const float*)d_in[4];
    const float* Wih1 = (const float*)d_in[5];
    const float* Whh1 = (const float*)d_in[6];
    const float* bih1 = (const float*)d_in[7];
    const float* bhh1 = (const float*)d_in[8];
    const float* Wfc  = (const float*)d_in[9];
    const float* bfc  = (const float*)d_in[10];
    float* out = (float*)d_out;

    lstm2_fused<<<dim3(NBLK), dim3(NTH), SM_BYTES, stream>>>(
        x, Wih0, Whh0, bih0, bhh0, Wih1, Whh1, bih1, bhh1, Wfc, bfc, out);
}